// Round 4
// baseline (126.959 us; speedup 1.0000x reference)
//
#include <hip/hip_runtime.h>

// ---------------------------------------------------------------------------
// QnnFormerVQC: 4-qubit VQC, B=262144. Inputs FP32, output FP32 (round-3
// evidence: bf16 reads of inputs -> NaN => inputs are fp32).
//
// ROUND-3 BUG FIX: the reference's _apmcx(psi,[0,1,2],3) indexing
// (Ellipsis,1,1,1) aligns to the LAST three axes (q1,q2,q3), reversing q0.
// So the "MCX" swaps amplitudes 7<->15 (target qubit 0, controls q1,q2,q3),
// NOT 14<->15. Both previous rounds shared the 14<->15 error -> identical
// absmax 1.98.
//
// Design: everything past the RY(x) encoding is batch-independent.
//   qnn_prep: 1 wave, 16 active lanes; lane j evolves basis column e_j fully
//             in registers (no barriers) through the literal gate sequence;
//             writes 16x16 complex U to d_ws.
//   qnn_main: per element v = kron_q [cos(x_q/2), sin(x_q/2)] (real),
//             psi = U v, then 12 observables (z,x,y per qubit).
// ---------------------------------------------------------------------------

// Apply 2x2 complex gate to bit m (qubit 3-m), optional control mask.
__device__ __forceinline__ void g1(float* sr, float* si, const int m,
                                   float m00r, float m00i, float m01r, float m01i,
                                   float m10r, float m10i, float m11r, float m11i,
                                   const int cmask) {
    const int mask = 1 << m;
#pragma unroll
    for (int p = 0; p < 8; ++p) {
        const int i0 = ((p >> m) << (m + 1)) | (p & (mask - 1));
        const int i1 = i0 | mask;
        if ((i0 & cmask) != cmask) continue;   // compile-time folded
        const float xr = sr[i0], xi = si[i0];
        const float yr = sr[i1], yi = si[i1];
        sr[i0] = m00r * xr - m00i * xi + m01r * yr - m01i * yi;
        si[i0] = m00r * xi + m00i * xr + m01r * yi + m01i * yr;
        sr[i1] = m10r * xr - m10i * xi + m11r * yr - m11i * yi;
        si[i1] = m10r * xi + m10i * xr + m11r * yi + m11i * yr;
    }
}

// Literal circuit body (everything AFTER the RY(x) encoding).
__device__ __forceinline__ void evolve(float* sr, float* si,
                                       const float* __restrict__ W,
                                       const float* __restrict__ E,
                                       const float* __restrict__ G,
                                       const float* __restrict__ Bt) {
    const float R = 0.70710678118654752440f;
    for (int l = 0; l < 3; ++l) {
        // RX, RY, RZ with weights[l][q]
#pragma unroll
        for (int q = 0; q < 4; ++q) {
            float c, s;
            __sincosf(0.5f * W[l * 4 + q], &s, &c);
            g1(sr, si, 3 - q, c, 0.f, 0.f, -s, 0.f, -s, c, 0.f, 0);  // RX
            g1(sr, si, 3 - q, c, 0.f, -s, 0.f, s, 0.f, c, 0.f, 0);   // RY
            g1(sr, si, 3 - q, c, -s, 0.f, 0.f, 0.f, 0.f, c, s, 0);   // RZ
        }
        // CRX chain: control i, target (i+1)%4
#pragma unroll
        for (int i = 0; i < 4; ++i) {
            float c, s;
            __sincosf(0.5f * E[l * 4 + i], &s, &c);
            g1(sr, si, 3 - ((i + 1) & 3),
               c, 0.f, 0.f, -s, 0.f, -s, c, 0.f, 1 << (3 - i));      // CRX
        }
        // H all
#pragma unroll
        for (int q = 0; q < 4; ++q)
            g1(sr, si, 3 - q, R, 0.f, R, 0.f, R, 0.f, -R, 0.f, 0);
        // X all
#pragma unroll
        for (int q = 0; q < 4; ++q)
            g1(sr, si, 3 - q, 0.f, 0.f, 1.f, 0.f, 1.f, 0.f, 0.f, 0.f, 0);
        // H(qubit 3) = bit 0
        g1(sr, si, 0, R, 0.f, R, 0.f, R, 0.f, -R, 0.f, 0);
        // reference "MCX": swap amps 7 <-> 15 (q0 flips when q1=q2=q3=1)
        {
            float tr = sr[7], ti = si[7];
            sr[7] = sr[15]; si[7] = si[15];
            sr[15] = tr;    si[15] = ti;
        }
        // H(qubit 3)
        g1(sr, si, 0, R, 0.f, R, 0.f, R, 0.f, -R, 0.f, 0);
        // X all
#pragma unroll
        for (int q = 0; q < 4; ++q)
            g1(sr, si, 3 - q, 0.f, 0.f, 1.f, 0.f, 1.f, 0.f, 0.f, 0.f, 0);
        // H all
#pragma unroll
        for (int q = 0; q < 4; ++q)
            g1(sr, si, 3 - q, R, 0.f, R, 0.f, R, 0.f, -R, 0.f, 0);
        // CX(i,i+1), RZ(g) on i+1, CX(i,i+1) for i=0..2
        {
            float cg, sg;
            __sincosf(0.5f * G[l], &sg, &cg);
#pragma unroll
            for (int i = 0; i < 3; ++i) {
                const int cm = 1 << (3 - i);
                const int m  = 3 - (i + 1);
                g1(sr, si, m, 0.f, 0.f, 1.f, 0.f, 1.f, 0.f, 0.f, 0.f, cm); // CX
                g1(sr, si, m, cg, -sg, 0.f, 0.f, 0.f, 0.f, cg, sg, 0);     // RZ
                g1(sr, si, m, 0.f, 0.f, 1.f, 0.f, 1.f, 0.f, 0.f, 0.f, cm); // CX
            }
        }
        // RX(beta) all
        {
            float cb, sb;
            __sincosf(0.5f * Bt[l], &sb, &cb);
#pragma unroll
            for (int q = 0; q < 4; ++q)
                g1(sr, si, 3 - q, cb, 0.f, 0.f, -sb, 0.f, -sb, cb, 0.f, 0);
        }
    }
}

// One wave; lanes 0..15 each evolve one basis column in registers.
__global__ void qnn_prep(const float* __restrict__ W, const float* __restrict__ E,
                         const float* __restrict__ G, const float* __restrict__ Bt,
                         float* __restrict__ Uout) {   // Ur[256] then Ui[256]
    const int col = threadIdx.x;
    if (col >= 16) return;
    float sr[16], si[16];
#pragma unroll
    for (int i = 0; i < 16; ++i) { sr[i] = (i == col) ? 1.f : 0.f; si[i] = 0.f; }
    evolve(sr, si, W, E, G, Bt);
#pragma unroll
    for (int i = 0; i < 16; ++i) {
        Uout[i * 16 + col]       = sr[i];
        Uout[256 + i * 16 + col] = si[i];
    }
}

__global__ __launch_bounds__(256) void qnn_main(const float* __restrict__ x,
                                                const float* __restrict__ U,
                                                float* __restrict__ out, int B) {
    const int b = blockIdx.x * 256 + threadIdx.x;
    if (b >= B) return;

    const float4 xv = reinterpret_cast<const float4*>(x)[b];
    float c0, s0, c1, s1, c2, s2, c3, s3;
    __sincosf(0.5f * xv.x, &s0, &c0);
    __sincosf(0.5f * xv.y, &s1, &c1);
    __sincosf(0.5f * xv.z, &s2, &c2);
    __sincosf(0.5f * xv.w, &s3, &c3);

    const float t01[4] = { c0 * c1, c0 * s1, s0 * c1, s0 * s1 };
    const float t23[4] = { c2 * c3, c2 * s3, s2 * c3, s2 * s3 };
    float v[16];
#pragma unroll
    for (int i = 0; i < 16; ++i) v[i] = t01[i >> 2] * t23[i & 3];

    // psi = U v  (U wave-uniform -> scalar loads)
    float pr[16], pi[16];
#pragma unroll
    for (int i = 0; i < 16; ++i) {
        float ar = 0.f, ai = 0.f;
#pragma unroll
        for (int j = 0; j < 16; ++j) {
            ar = fmaf(U[i * 16 + j], v[j], ar);
            ai = fmaf(U[256 + i * 16 + j], v[j], ai);
        }
        pr[i] = ar;
        pi[i] = ai;
    }

    float n[16];
#pragma unroll
    for (int i = 0; i < 16; ++i) n[i] = pr[i] * pr[i] + pi[i] * pi[i];

    float o[12];
#pragma unroll
    for (int q = 0; q < 4; ++q) {
        const int m = 3 - q;
        const int mask = 1 << m;
        float z = 0.f, cr = 0.f, ci = 0.f;
#pragma unroll
        for (int p = 0; p < 8; ++p) {
            const int i0 = ((p >> m) << (m + 1)) | (p & (mask - 1));
            const int i1 = i0 | mask;
            z  += n[i0] - n[i1];
            cr += pr[i0] * pr[i1] + pi[i0] * pi[i1];   // Re(conj(a)·d)
            ci += pr[i0] * pi[i1] - pi[i0] * pr[i1];   // Im(conj(a)·d)
        }
        o[q]     = z;
        o[4 + q] = 2.f * cr;
        o[8 + q] = 2.f * ci;
    }

    float4* op = reinterpret_cast<float4*>(out + (size_t)b * 12);
    op[0] = make_float4(o[0], o[1], o[2],  o[3]);
    op[1] = make_float4(o[4], o[5], o[6],  o[7]);
    op[2] = make_float4(o[8], o[9], o[10], o[11]);
}

extern "C" void kernel_launch(void* const* d_in, const int* in_sizes, int n_in,
                              void* d_out, int out_size, void* d_ws, size_t ws_size,
                              hipStream_t stream) {
    const float* x  = (const float*)d_in[0];
    const float* W  = (const float*)d_in[1];
    const float* E  = (const float*)d_in[2];
    const float* G  = (const float*)d_in[3];
    const float* Bt = (const float*)d_in[4];
    float* U   = (float*)d_ws;   // 512 floats
    float* out = (float*)d_out;
    const int B = in_sizes[0] / 4;

    hipLaunchKernelGGL(qnn_prep, dim3(1), dim3(64), 0, stream, W, E, G, Bt, U);
    hipLaunchKernelGGL(qnn_main, dim3((B + 255) / 256), dim3(256), 0, stream,
                       x, U, out, B);
}

// Round 5
// 78.017 us; speedup vs baseline: 1.6273x; 1.6273x over previous
//
#include <hip/hip_runtime.h>

// ---------------------------------------------------------------------------
// QnnFormerVQC: 4-qubit VQC, B=262144, fp32 in / fp32 out.
// Round-4 passed (absmax 0.0039) but prep kernel was icache-fetch-bound
// (67 us, single wave, ~60KB unrolled body) and main's uniform U loads were
// not scalarized (~55 us). Round 5: ONE fused kernel.
//   - Each block rebuilds the 16x16 circuit unitary U with a lane-parallel
//     shuffle circuit: thread=(col,amp), gate = shfl_xor + few FMA. ~1.5k
//     instr/wave, tiny code.
//   - U goes to LDS, then each lane register-caches an 8-float slice;
//     U[i][j] is read via __builtin_amdgcn_readlane (compile-time lane) ->
//     SGPR operand of v_fma. No memory traffic in the 512-MAC matvec.
//   - 2 batch elements per thread so each readlane feeds 4 FMAs.
// Circuit semantics identical to the round-4 verified literal sequence
// (incl. the reference's _apmcx quirk: swap amps 7<->15, NOT 14<->15).
// ---------------------------------------------------------------------------

#define RL(x, l) __int_as_float(__builtin_amdgcn_readlane(__float_as_int(x), (l)))

// --- shuffle-gate helpers: lane holds one amplitude (ar,ai) of one column ---

// RX(theta): [[c,-is],[-is,c]] — same row formula for both halves.
__device__ __forceinline__ void g_rx(float& ar, float& ai, int amp, int m,
                                     float c, float s, int cmask) {
    const float br = __shfl_xor(ar, 1 << m, 64);
    const float bi = __shfl_xor(ai, 1 << m, 64);
    const float nr = c * ar + s * bi;
    const float ni = c * ai - s * br;
    const bool act = (amp & cmask) == cmask;
    ar = act ? nr : ar;
    ai = act ? ni : ai;
}

// RY(theta): [[c,-s],[s,c]] real.
__device__ __forceinline__ void g_ry(float& ar, float& ai, int amp, int m,
                                     float c, float s) {
    const float br = __shfl_xor(ar, 1 << m, 64);
    const float bi = __shfl_xor(ai, 1 << m, 64);
    const float sp = ((amp >> m) & 1) ? s : -s;
    ar = c * ar + sp * br;
    ai = c * ai + sp * bi;
}

// RZ(theta): diag(e^{-i t/2}, e^{+i t/2}) — no shuffle.
__device__ __forceinline__ void g_rz(float& ar, float& ai, int amp, int m,
                                     float c, float s) {
    const float p = ((amp >> m) & 1) ? s : -s;
    const float nr = c * ar - p * ai;
    const float ni = c * ai + p * ar;
    ar = nr; ai = ni;
}

// Hadamard.
__device__ __forceinline__ void g_h(float& ar, float& ai, int amp, int m) {
    const float R = 0.70710678118654752440f;
    const float br = __shfl_xor(ar, 1 << m, 64);
    const float bi = __shfl_xor(ai, 1 << m, 64);
    const bool hi = (amp >> m) & 1;
    ar = hi ? R * (br - ar) : R * (ar + br);
    ai = hi ? R * (bi - ai) : R * (ai + bi);
}

// X / CX / MCX: take partner's value when active.
__device__ __forceinline__ void g_swap(float& ar, float& ai, int m, bool act) {
    const float br = __shfl_xor(ar, 1 << m, 64);
    const float bi = __shfl_xor(ai, 1 << m, 64);
    ar = act ? br : ar;
    ai = act ? bi : ai;
}

// --- observables from psi (verified in round 4) ---
__device__ __forceinline__ void emit_obs(const float* pr, const float* pi,
                                         float* __restrict__ out, int b) {
    float n[16];
#pragma unroll
    for (int i = 0; i < 16; ++i) n[i] = pr[i] * pr[i] + pi[i] * pi[i];
    float o[12];
#pragma unroll
    for (int q = 0; q < 4; ++q) {
        const int m = 3 - q;
        const int mask = 1 << m;
        float z = 0.f, cr = 0.f, ci = 0.f;
#pragma unroll
        for (int p = 0; p < 8; ++p) {
            const int i0 = ((p >> m) << (m + 1)) | (p & (mask - 1));
            const int i1 = i0 | mask;
            z  += n[i0] - n[i1];
            cr += pr[i0] * pr[i1] + pi[i0] * pi[i1];
            ci += pr[i0] * pi[i1] - pi[i0] * pr[i1];
        }
        o[q]     = z;
        o[4 + q] = 2.f * cr;
        o[8 + q] = 2.f * ci;
    }
    float4* op = reinterpret_cast<float4*>(out + (size_t)b * 12);
    op[0] = make_float4(o[0], o[1], o[2],  o[3]);
    op[1] = make_float4(o[4], o[5], o[6],  o[7]);
    op[2] = make_float4(o[8], o[9], o[10], o[11]);
}

__global__ __launch_bounds__(256, 2)
void qnn_fused(const float* __restrict__ x,
               const float* __restrict__ W,  const float* __restrict__ E,
               const float* __restrict__ G,  const float* __restrict__ Bt,
               float* __restrict__ out, int half) {
    __shared__ float2 cs[30];      // (cos,sin) of half-angles of all params
    __shared__ float  Upack[512];  // U[i][j]: re at i*32+2j, im at +1

    const int tid = threadIdx.x;

    // --- stage 0: 30 threads compute all parameter sincos once ---
    if (tid < 30) {
        float th;
        if (tid < 12)      th = W[tid];
        else if (tid < 24) th = E[tid - 12];
        else if (tid < 27) th = G[tid - 24];
        else               th = Bt[tid - 27];
        float s, c;
        __sincosf(0.5f * th, &s, &c);
        cs[tid] = make_float2(c, s);
    }
    __syncthreads();

    // --- stage 1: build U. thread = (col 0..15, amp 0..15); shfl partners
    //     share the same col since amp = lane&15. ---
    const int col = tid >> 4;
    const int amp = tid & 15;
    float ar = (amp == col) ? 1.f : 0.f;
    float ai = 0.f;

    for (int l = 0; l < 3; ++l) {
        // RX,RY,RZ (same angle weights[l][q]), qubit q -> bit 3-q
#pragma unroll
        for (int q = 0; q < 4; ++q) {
            const float2 cw = cs[l * 4 + q];
            g_rx(ar, ai, amp, 3 - q, cw.x, cw.y, 0);
            g_ry(ar, ai, amp, 3 - q, cw.x, cw.y);
            g_rz(ar, ai, amp, 3 - q, cw.x, cw.y);
        }
        // CRX chain: control i, target (i+1)%4
#pragma unroll
        for (int i = 0; i < 4; ++i) {
            const float2 ce = cs[12 + l * 4 + i];
            g_rx(ar, ai, amp, 3 - ((i + 1) & 3), ce.x, ce.y, 1 << (3 - i));
        }
        // H all, X all
#pragma unroll
        for (int q = 0; q < 4; ++q) g_h(ar, ai, amp, 3 - q);
#pragma unroll
        for (int q = 0; q < 4; ++q) g_swap(ar, ai, 3 - q, true);
        // H(q3), reference "MCX" = swap amps 7<->15, H(q3)
        g_h(ar, ai, amp, 0);
        g_swap(ar, ai, 3, (amp & 7) == 7);
        g_h(ar, ai, amp, 0);
        // X all, H all
#pragma unroll
        for (int q = 0; q < 4; ++q) g_swap(ar, ai, 3 - q, true);
#pragma unroll
        for (int q = 0; q < 4; ++q) g_h(ar, ai, amp, 3 - q);
        // CX(i,i+1) RZ(gamma on i+1) CX(i,i+1), i=0..2
        {
            const float2 cg = cs[24 + l];
#pragma unroll
            for (int i = 0; i < 3; ++i) {
                const int cm = 1 << (3 - i);
                const int m  = 2 - i;           // bit of qubit i+1
                g_swap(ar, ai, m, (amp & cm) == cm);
                g_rz(ar, ai, amp, m, cg.x, cg.y);
                g_swap(ar, ai, m, (amp & cm) == cm);
            }
        }
        // RX(beta) all
        {
            const float2 cb = cs[27 + l];
#pragma unroll
            for (int q = 0; q < 4; ++q) g_rx(ar, ai, amp, 3 - q, cb.x, cb.y, 0);
        }
    }

    // lane (col,amp) holds U[amp][col]
    Upack[amp * 32 + 2 * col]     = ar;
    Upack[amp * 32 + 2 * col + 1] = ai;
    __syncthreads();

    // --- stage 2: each lane register-caches 8 floats of U ---
    const int lane = tid & 63;
    const float4 ua = *reinterpret_cast<const float4*>(&Upack[lane * 8]);
    const float4 ub = *reinterpret_cast<const float4*>(&Upack[lane * 8 + 4]);
    const float u[8] = { ua.x, ua.y, ua.z, ua.w, ub.x, ub.y, ub.z, ub.w };

    // --- stage 3: two batch elements per thread ---
    const int b0 = blockIdx.x * 256 + tid;
    const int b1 = b0 + half;

    const float4 x0 = reinterpret_cast<const float4*>(x)[b0];
    const float4 x1 = reinterpret_cast<const float4*>(x)[b1];

    float v0[16], v1[16];
    {
        float c0, s0, c1, s1, c2, s2, c3, s3;
        __sincosf(0.5f * x0.x, &s0, &c0);
        __sincosf(0.5f * x0.y, &s1, &c1);
        __sincosf(0.5f * x0.z, &s2, &c2);
        __sincosf(0.5f * x0.w, &s3, &c3);
        const float t01[4] = { c0 * c1, c0 * s1, s0 * c1, s0 * s1 };
        const float t23[4] = { c2 * c3, c2 * s3, s2 * c3, s2 * s3 };
#pragma unroll
        for (int i = 0; i < 16; ++i) v0[i] = t01[i >> 2] * t23[i & 3];
    }
    {
        float c0, s0, c1, s1, c2, s2, c3, s3;
        __sincosf(0.5f * x1.x, &s0, &c0);
        __sincosf(0.5f * x1.y, &s1, &c1);
        __sincosf(0.5f * x1.z, &s2, &c2);
        __sincosf(0.5f * x1.w, &s3, &c3);
        const float t01[4] = { c0 * c1, c0 * s1, s0 * c1, s0 * s1 };
        const float t23[4] = { c2 * c3, c2 * s3, s2 * c3, s2 * s3 };
#pragma unroll
        for (int i = 0; i < 16; ++i) v1[i] = t01[i >> 2] * t23[i & 3];
    }

    // psi = U v for both elements; coefficients via readlane -> SGPR FMA
    float pr0[16], pi0[16], pr1[16], pi1[16];
#pragma unroll
    for (int i = 0; i < 16; ++i) {
        float a0r = 0.f, a0i = 0.f, a1r = 0.f, a1i = 0.f;
#pragma unroll
        for (int j = 0; j < 16; ++j) {
            const int f = i * 32 + 2 * j;
            const float sUr = RL(u[f & 7], f >> 3);
            const float sUi = RL(u[(f & 7) + 1], f >> 3);
            a0r = fmaf(sUr, v0[j], a0r);
            a0i = fmaf(sUi, v0[j], a0i);
            a1r = fmaf(sUr, v1[j], a1r);
            a1i = fmaf(sUi, v1[j], a1i);
        }
        pr0[i] = a0r; pi0[i] = a0i;
        pr1[i] = a1r; pi1[i] = a1i;
    }

    emit_obs(pr0, pi0, out, b0);
    emit_obs(pr1, pi1, out, b1);
}

extern "C" void kernel_launch(void* const* d_in, const int* in_sizes, int n_in,
                              void* d_out, int out_size, void* d_ws, size_t ws_size,
                              hipStream_t stream) {
    const float* x  = (const float*)d_in[0];
    const float* W  = (const float*)d_in[1];
    const float* E  = (const float*)d_in[2];
    const float* G  = (const float*)d_in[3];
    const float* Bt = (const float*)d_in[4];
    float* out = (float*)d_out;
    (void)d_ws; (void)ws_size;

    const int B = in_sizes[0] / 4;       // 262144
    const int half = B / 2;              // 2 elements per thread
    const int blocks = half / 256;       // 512

    hipLaunchKernelGGL(qnn_fused, dim3(blocks), dim3(256), 0, stream,
                       x, W, E, G, Bt, out, half);
}